// Round 8
// baseline (304.358 us; speedup 1.0000x reference)
//
#include <hip/hip_runtime.h>

typedef int v4i __attribute__((ext_vector_type(4)));

#define KDIM 2048
#define NDIM 2048

#define GLOAD16(g, l) __builtin_amdgcn_global_load_lds(                      \
    (const __attribute__((address_space(1))) void*)(g),                      \
    (__attribute__((address_space(3))) void*)(l), 16, 0, 0)

// ---------------- quant kernels ----------------

__device__ __forceinline__ int pack4q(float4 v, float s) {
  int a = __float2int_rn(v.x * s);
  int b = __float2int_rn(v.y * s);
  int c = __float2int_rn(v.z * s);
  int d = __float2int_rn(v.w * s);
  a = max(-128, min(127, a)); b = max(-128, min(127, b));
  c = max(-128, min(127, c)); d = max(-128, min(127, d));
  return (a & 0xff) | ((b & 0xff) << 8) | ((c & 0xff) << 16) | ((d & 0xff) << 24);
}

__global__ __launch_bounds__(256) void quant_rows(const float* __restrict__ x,
                                                  signed char* __restrict__ q,
                                                  float* __restrict__ rscale) {
  const int row = blockIdx.x;
  const float4* xr = (const float4*)(x + (size_t)row * KDIM);
  float4 v0 = xr[threadIdx.x];
  float4 v1 = xr[256 + threadIdx.x];
  float m = fmaxf(fmaxf(fabsf(v0.x), fabsf(v0.y)), fmaxf(fabsf(v0.z), fabsf(v0.w)));
  m = fmaxf(m, fmaxf(fmaxf(fabsf(v1.x), fabsf(v1.y)), fmaxf(fabsf(v1.z), fabsf(v1.w))));
  #pragma unroll
  for (int off = 32; off > 0; off >>= 1) m = fmaxf(m, __shfl_xor(m, off));
  __shared__ float red[4];
  if ((threadIdx.x & 63) == 0) red[threadIdx.x >> 6] = m;
  __syncthreads();
  float xmax = fmaxf(fmaxf(red[0], red[1]), fmaxf(red[2], red[3]));
  xmax = fmaxf(xmax, 1e-5f);
  const float scale = 127.0f / xmax;
  int* qr = (int*)(q + (size_t)row * KDIM);
  qr[threadIdx.x] = pack4q(v0, scale);
  qr[256 + threadIdx.x] = pack4q(v1, scale);
  if (threadIdx.x == 0) rscale[row] = xmax * (1.0f / 127.0f);
}

__global__ __launch_bounds__(256) void quant_w(const float* __restrict__ W,
                                               signed char* __restrict__ Wq) {
  const int i = blockIdx.x * 256 + threadIdx.x;
  float4 v = ((const float4*)W)[i];
  int a = (int)v.x, b = (int)v.y, c = (int)v.z, d = (int)v.w;
  ((int*)Wq)[i] = (a & 0xff) | ((b & 0xff) << 8) | ((c & 0xff) << 16) | ((d & 0xff) << 24);
}

// ---- 128x256 4-wave i8 GEMM: A DIRECT FROM GLOBAL (reg-dbuf), B-only LDS ring-3 ----
// Round-8 change: A-fragments bypass LDS entirely. Lane l loads 16 B at
// row (l&15)+m*16, kbytes (l>>4)*16 — global_load_dwordx4 lands directly in the
// MFMA A-operand layout. A(t+1) loads issue during tile t (reg double-buffer).
// DS pipe now carries only B: 8 ds_read_b128 + 16 KB staging per block-tile (-33%).
// LDS = 3 x 16 KB B-ring -> 48 KB, 2 blocks/CU.
// vmcnt ladder: tile t issues A(t+1) x4 then B-stage(t+2) x4; end-of-tile vmcnt(4)
// proves B(t+1)+A(t+1) complete, leaves B(t+2) in flight. Drain only in tail.
// B LDS swizzle (verified 0-conflict R4/R7): phys 16B slot = logical ^ ((row>>1)&3),
// applied on global source (global_load_lds dest linear) and ds_read addrs.

#define VM4 asm volatile("s_waitcnt vmcnt(4)" ::: "memory")
#define VM0 asm volatile("s_waitcnt vmcnt(0)" ::: "memory")
#define VMNONE

// B ring buffer stride 16384: B[256][64B], row-linear
#define STAGE_B(U, T)                                                        \
  GLOAD16(sb + (T) * 64,              lds + (U) * 16384 + dstw);             \
  GLOAD16(sb + (T) * 64 +  64 * KDIM, lds + (U) * 16384 + 4096 + dstw);     \
  GLOAD16(sb + (T) * 64 + 128 * KDIM, lds + (U) * 16384 + 8192 + dstw);     \
  GLOAD16(sb + (T) * 64 + 192 * KDIM, lds + (U) * 16384 + 12288 + dstw);

#define MF1(m, n, A, BF) acc[m][n] = __builtin_amdgcn_mfma_i32_16x16x64_i8((A), (BF), acc[m][n], 0, 0, 0);

// Tile t: consume B from buf U and A-frags CA0..3; load A(t+1) into NA0..3;
// stage B(t+2) into buf (U+2)%3.
#define KTILE(U, T, CA, NA, DOREAD, DOSTAGE, VMEND)                          \
  {                                                                          \
    if (DOREAD) {                                                            \
      NA##0 = *(const v4i*)(pa0 + ((T) + 1) * 64);                           \
      NA##1 = *(const v4i*)(pa1 + ((T) + 1) * 64);                           \
      NA##2 = *(const v4i*)(pa2 + ((T) + 1) * 64);                           \
      NA##3 = *(const v4i*)(pa3 + ((T) + 1) * 64);                           \
    }                                                                        \
    if (DOSTAGE) { STAGE_B((((U) + 2) % 3), (T) + 2) }                       \
    v4i b0 = *(const v4i*)(lds + (U) * 16384 + bRd);                         \
    v4i b1 = *(const v4i*)(lds + (U) * 16384 + bRd + 1024);                  \
    v4i b2 = *(const v4i*)(lds + (U) * 16384 + bRd + 2048);                  \
    v4i b3 = *(const v4i*)(lds + (U) * 16384 + bRd + 3072);                  \
    v4i b4 = *(const v4i*)(lds + (U) * 16384 + bRd + 4096);                  \
    v4i b5 = *(const v4i*)(lds + (U) * 16384 + bRd + 5120);                  \
    v4i b6 = *(const v4i*)(lds + (U) * 16384 + bRd + 6144);                  \
    v4i b7 = *(const v4i*)(lds + (U) * 16384 + bRd + 7168);                  \
    __builtin_amdgcn_s_setprio(1);                                           \
    MF1(0, 0, CA##0, b0) MF1(0, 1, CA##0, b1) MF1(0, 2, CA##0, b2) MF1(0, 3, CA##0, b3) \
    MF1(0, 4, CA##0, b4) MF1(0, 5, CA##0, b5) MF1(0, 6, CA##0, b6) MF1(0, 7, CA##0, b7) \
    MF1(1, 0, CA##1, b0) MF1(1, 1, CA##1, b1) MF1(1, 2, CA##1, b2) MF1(1, 3, CA##1, b3) \
    MF1(1, 4, CA##1, b4) MF1(1, 5, CA##1, b5) MF1(1, 6, CA##1, b6) MF1(1, 7, CA##1, b7) \
    MF1(2, 0, CA##2, b0) MF1(2, 1, CA##2, b1) MF1(2, 2, CA##2, b2) MF1(2, 3, CA##2, b3) \
    MF1(2, 4, CA##2, b4) MF1(2, 5, CA##2, b5) MF1(2, 6, CA##2, b6) MF1(2, 7, CA##2, b7) \
    MF1(3, 0, CA##3, b0) MF1(3, 1, CA##3, b1) MF1(3, 2, CA##3, b2) MF1(3, 3, CA##3, b3) \
    MF1(3, 4, CA##3, b4) MF1(3, 5, CA##3, b5) MF1(3, 6, CA##3, b6) MF1(3, 7, CA##3, b7) \
    __builtin_amdgcn_s_setprio(0);                                           \
    VMEND;                                                                   \
    __builtin_amdgcn_s_barrier();                                            \
    __builtin_amdgcn_sched_barrier(0);                                       \
  }

__global__ __launch_bounds__(256, 2) void gemm_i8(const signed char* __restrict__ A,
                                                  const signed char* __restrict__ B,
                                                  const float* __restrict__ rscale,
                                                  float* __restrict__ C) {
  __shared__ __align__(16) signed char lds[3 * 16384];  // 48 KB -> 2 blocks/CU
  const int bid = blockIdx.x;
  const int lid = (bid & 7) * 256 + (bid >> 3);  // bijective XCD swizzle (2048 % 8 == 0)
  const int bm = lid >> 3;                       // 256 row tiles (M/128)
  const int bn = lid & 7;                        // 8 col tiles (N/256)
  const int tid = threadIdx.x;
  const int wid = tid >> 6;
  const int lane = tid & 63;
  const int wr = wid >> 1, wc = wid & 1;         // wave-tile 64 rows x 128 cols

  // B staging: per gload, thread covers row = base + wid*16 + (lane>>2),
  // dest slot = lane&3 (HW linear). Source logical slot = (lane&3) ^ ((row>>1)&3).
  const int srow = wid * 16 + (lane >> 2);
  const int scol = (((lane & 3) ^ ((lane >> 3) & 3)) << 4);
  const signed char* sb = B + (size_t)(bn * 256 + srow) * KDIM + scol;
  const int dstw = wid << 10;  // wave-uniform LDS chunk; HW adds lane*16

  // B ds_read: logical k-slot = lane>>4, row = ...+(lane&15) -> physical slot
  // = (lane>>4) ^ ((lane>>1)&3).
  const int rslot = (((lane >> 4) ^ ((lane >> 1) & 3)) << 4);
  const int bRd = (wc * 128 + (lane & 15)) * 64 + rslot;

  // A-frag direct-load pointers (m = 0..3): row = bm*128 + wr*64 + m*16 + (lane&15),
  // kbytes = (lane>>4)*16 — matches MFMA A-operand layout exactly.
  const size_t abase = (size_t)(bm * 128 + wr * 64 + (lane & 15)) * KDIM + ((lane >> 4) << 4);
  const signed char* pa0 = A + abase;
  const signed char* pa1 = A + abase + (size_t)16 * KDIM;
  const signed char* pa2 = A + abase + (size_t)32 * KDIM;
  const signed char* pa3 = A + abase + (size_t)48 * KDIM;

  v4i acc[4][8] = {};
  v4i fX0, fX1, fX2, fX3, fY0, fY1, fY2, fY3;

  // prologue: A(0) x4, then stage B(0), B(1); vmcnt(4) => A(0)+B(0) done, B(1) in flight.
  fX0 = *(const v4i*)(pa0);
  fX1 = *(const v4i*)(pa1);
  fX2 = *(const v4i*)(pa2);
  fX3 = *(const v4i*)(pa3);
  STAGE_B(0, 0)
  STAGE_B(1, 1)
  VM4;
  __builtin_amdgcn_s_barrier();
  __builtin_amdgcn_sched_barrier(0);

  // 32 K-tiles; ring mod 3; A-frag sets alternate fX/fY per tile. Unroll by 6
  // so both the mod-3 ring and the mod-2 frag alternation stay in phase.
  for (int ti = 0; ti < 5; ++ti) {
    const int t = ti * 6;
    KTILE(0, t + 0, fX, fY, 1, 1, VM4)
    KTILE(1, t + 1, fY, fX, 1, 1, VM4)
    KTILE(2, t + 2, fX, fY, 1, 1, VM4)
    KTILE(0, t + 3, fY, fX, 1, 1, VM4)
    KTILE(1, t + 4, fX, fY, 1, 1, VM4)
    KTILE(2, t + 5, fY, fX, 1, 1, VM4)
  }
  // t=30: loads A(31), no stage; drain all (B(31)+A(31)). t=31: pure compute.
  KTILE(0, 30, fX, fY, 1, 0, VM0)
  KTILE(1, 31, fY, fX, 0, 0, VMNONE)

  // epilogue: C/D layout col = lane&15, row = (lane>>4)*4 + reg
  const int col0 = bn * 256 + wc * 128 + (lane & 15);
  const int rbase = bm * 128 + wr * 64 + ((lane >> 4) << 2);
  #pragma unroll
  for (int m = 0; m < 4; ++m) {
    #pragma unroll
    for (int r = 0; r < 4; ++r) {
      const int row = rbase + m * 16 + r;
      const float s = rscale[row];
      float* crow = C + (size_t)row * NDIM + col0;
      #pragma unroll
      for (int n = 0; n < 8; ++n) crow[n * 16] = (float)acc[m][n][r] * s;
    }
  }
}

extern "C" void kernel_launch(void* const* d_in, const int* in_sizes, int n_in,
                              void* d_out, int out_size, void* d_ws, size_t ws_size,
                              hipStream_t stream) {
  const float* x = (const float*)d_in[0];
  const float* W = (const float*)d_in[1];
  float* out = (float*)d_out;
  const int M = in_sizes[0] / KDIM;  // 32768

  signed char* q = (signed char*)d_ws;                       // M*K   = 64 MB
  signed char* Wq = q + (size_t)M * KDIM;                    // N*K   =  4 MB
  float* rscale = (float*)(Wq + (size_t)NDIM * KDIM);        // M*4   = 128 KB

  quant_rows<<<M, 256, 0, stream>>>(x, q, rscale);
  quant_w<<<(NDIM * KDIM / 4) / 256, 256, 0, stream>>>(W, Wq);
  gemm_i8<<<(M / 128) * (NDIM / 256), 256, 0, stream>>>(q, Wq, rscale, out);
}

// Round 9
// 280.376 us; speedup vs baseline: 1.0855x; 1.0855x over previous
//
#include <hip/hip_runtime.h>

typedef int v4i __attribute__((ext_vector_type(4)));

#define KDIM 2048
#define NDIM 2048

#define GLOAD16(g, l) __builtin_amdgcn_global_load_lds(                      \
    (const __attribute__((address_space(1))) void*)(g),                      \
    (__attribute__((address_space(3))) void*)(l), 16, 0, 0)

// ---------------- quant kernels ----------------

__device__ __forceinline__ int pack4q(float4 v, float s) {
  int a = __float2int_rn(v.x * s);
  int b = __float2int_rn(v.y * s);
  int c = __float2int_rn(v.z * s);
  int d = __float2int_rn(v.w * s);
  a = max(-128, min(127, a)); b = max(-128, min(127, b));
  c = max(-128, min(127, c)); d = max(-128, min(127, d));
  return (a & 0xff) | ((b & 0xff) << 8) | ((c & 0xff) << 16) | ((d & 0xff) << 24);
}

__global__ __launch_bounds__(256) void quant_rows(const float* __restrict__ x,
                                                  signed char* __restrict__ q,
                                                  float* __restrict__ rscale) {
  const int row = blockIdx.x;
  const float4* xr = (const float4*)(x + (size_t)row * KDIM);
  float4 v0 = xr[threadIdx.x];
  float4 v1 = xr[256 + threadIdx.x];
  float m = fmaxf(fmaxf(fabsf(v0.x), fabsf(v0.y)), fmaxf(fabsf(v0.z), fabsf(v0.w)));
  m = fmaxf(m, fmaxf(fmaxf(fabsf(v1.x), fabsf(v1.y)), fmaxf(fabsf(v1.z), fabsf(v1.w))));
  #pragma unroll
  for (int off = 32; off > 0; off >>= 1) m = fmaxf(m, __shfl_xor(m, off));
  __shared__ float red[4];
  if ((threadIdx.x & 63) == 0) red[threadIdx.x >> 6] = m;
  __syncthreads();
  float xmax = fmaxf(fmaxf(red[0], red[1]), fmaxf(red[2], red[3]));
  xmax = fmaxf(xmax, 1e-5f);
  const float scale = 127.0f / xmax;
  int* qr = (int*)(q + (size_t)row * KDIM);
  qr[threadIdx.x] = pack4q(v0, scale);
  qr[256 + threadIdx.x] = pack4q(v1, scale);
  if (threadIdx.x == 0) rscale[row] = xmax * (1.0f / 127.0f);
}

// W (float {-1,0,1}) -> int8 packed in MFMA B-fragment layout:
// thread gid = ((bn*32 + kt)*16 + nf)*64 + lane produces 16 bytes:
//   W[bn*256 + nf*16 + (lane&15)][kt*64 + (lane>>4)*16 .. +16]
__global__ __launch_bounds__(256) void quant_w_pack(const float* __restrict__ W,
                                                    signed char* __restrict__ Bp) {
  const int gid = blockIdx.x * 256 + threadIdx.x;  // 0 .. 262143
  const int lane = gid & 63;
  const int f = gid >> 6;            // (bn*32+kt)*16 + nf
  const int nf = f & 15;
  const int bkt = f >> 4;            // bn*32 + kt
  const int kt = bkt & 31;
  const int bn = bkt >> 5;
  const int row = bn * 256 + nf * 16 + (lane & 15);
  const int k0 = kt * 64 + (lane >> 4) * 16;
  const float* src = W + (size_t)row * KDIM + k0;
  int out[4];
  #pragma unroll
  for (int j = 0; j < 4; ++j) {
    int b0 = (int)src[j * 4 + 0] & 0xff;
    int b1 = (int)src[j * 4 + 1] & 0xff;
    int b2 = (int)src[j * 4 + 2] & 0xff;
    int b3 = (int)src[j * 4 + 3] & 0xff;
    out[j] = b0 | (b1 << 8) | (b2 << 16) | (b3 << 24);
  }
  v4i o = { out[0], out[1], out[2], out[3] };
  *(v4i*)(Bp + (size_t)gid * 16) = o;
}

// ---- 256x256 8-wave i8 GEMM: A via LDS ring-3, B DIRECT from frag-packed global ----
// Round-9 change: B never touches LDS. quant_w_pack pre-arranged W so a wave's
// B-fragment is a coalesced global_load_dwordx4 (base + lane*16) from a 4 MB
// L2-resident buffer, double-buffered in regs under the counted-vmcnt ladder.
// DS pipe per CU-tile: A only (64 ds_read_b128 + 16 KB DMA-write ~ 900 cyc),
// now below the MFMA budget (1305 cyc/SIMD).
// Ladder: tile t issues B(t+1) x4 then A-stage S(t+2) x2; end-of-tile vmcnt(2)
// proves S(t+1)+B(t+1) complete, leaves S(t+2) in flight. Drain only at t=30.
// A LDS swizzle (verified 0-conflict R4/R7): phys 16B slot = logical ^ ((row>>1)&3),
// on global source (global_load_lds dest linear) and on ds_read addrs.

#define VM2 asm volatile("s_waitcnt vmcnt(2)" ::: "memory")
#define VM0 asm volatile("s_waitcnt vmcnt(0)" ::: "memory")
#define VMNONE

// A ring buffer stride 16384: A[256 rows][64 B], row-linear. Per wave 2 gloads
// cover rows [wid*32, wid*32+32).
#define STAGE(U, T)                                                          \
  GLOAD16(sa + (T) * 64,             lds + (U) * 16384 + dstw);              \
  GLOAD16(sa + (T) * 64 + 16 * KDIM, lds + (U) * 16384 + 1024 + dstw);

#define LOADB(P, T)                                                          \
  P##0 = *(const v4i*)(bp + (size_t)(T) * 16384);                            \
  P##1 = *(const v4i*)(bp + (size_t)(T) * 16384 + 1024);                     \
  P##2 = *(const v4i*)(bp + (size_t)(T) * 16384 + 2048);                     \
  P##3 = *(const v4i*)(bp + (size_t)(T) * 16384 + 3072);

#define MF1(m, n, A, BF) acc[m][n] = __builtin_amdgcn_mfma_i32_16x16x64_i8((A), (BF), acc[m][n], 0, 0, 0);

#define MFSET(CB)                                                            \
  __builtin_amdgcn_s_setprio(1);                                             \
  MF1(0, 0, a0, CB##0) MF1(0, 1, a0, CB##1) MF1(0, 2, a0, CB##2) MF1(0, 3, a0, CB##3) \
  MF1(1, 0, a1, CB##0) MF1(1, 1, a1, CB##1) MF1(1, 2, a1, CB##2) MF1(1, 3, a1, CB##3) \
  MF1(2, 0, a2, CB##0) MF1(2, 1, a2, CB##1) MF1(2, 2, a2, CB##2) MF1(2, 3, a2, CB##3) \
  MF1(3, 0, a3, CB##0) MF1(3, 1, a3, CB##1) MF1(3, 2, a3, CB##2) MF1(3, 3, a3, CB##3) \
  MF1(4, 0, a4, CB##0) MF1(4, 1, a4, CB##1) MF1(4, 2, a4, CB##2) MF1(4, 3, a4, CB##3) \
  MF1(5, 0, a5, CB##0) MF1(5, 1, a5, CB##1) MF1(5, 2, a5, CB##2) MF1(5, 3, a5, CB##3) \
  MF1(6, 0, a6, CB##0) MF1(6, 1, a6, CB##1) MF1(6, 2, a6, CB##2) MF1(6, 3, a6, CB##3) \
  MF1(7, 0, a7, CB##0) MF1(7, 1, a7, CB##1) MF1(7, 2, a7, CB##2) MF1(7, 3, a7, CB##3) \
  __builtin_amdgcn_s_setprio(0);

// Tile t: consume A from buf U (=t%3) and B set CB; load B(t+1) -> NB;
// stage S(t+2) -> buf (t+2)%3.
#define KTILE(U, T, CB, NB, DOB, DOSTAGE, VMEND)                             \
  {                                                                          \
    if (DOB) { LOADB(NB, (T) + 1) }                                          \
    if (DOSTAGE) { STAGE((((U) + 2) % 3), (T) + 2) }                         \
    v4i a0 = *(const v4i*)(lds + (U) * 16384 + aRd);                         \
    v4i a1 = *(const v4i*)(lds + (U) * 16384 + aRd + 1024);                  \
    v4i a2 = *(const v4i*)(lds + (U) * 16384 + aRd + 2048);                  \
    v4i a3 = *(const v4i*)(lds + (U) * 16384 + aRd + 3072);                  \
    v4i a4 = *(const v4i*)(lds + (U) * 16384 + aRd + 4096);                  \
    v4i a5 = *(const v4i*)(lds + (U) * 16384 + aRd + 5120);                  \
    v4i a6 = *(const v4i*)(lds + (U) * 16384 + aRd + 6144);                  \
    v4i a7 = *(const v4i*)(lds + (U) * 16384 + aRd + 7168);                  \
    MFSET(CB)                                                                \
    VMEND;                                                                   \
    __builtin_amdgcn_s_barrier();                                            \
    __builtin_amdgcn_sched_barrier(0);                                       \
  }

__global__ __launch_bounds__(512, 2) void gemm_i8(const signed char* __restrict__ A,
                                                  const signed char* __restrict__ Bp,
                                                  const float* __restrict__ rscale,
                                                  float* __restrict__ C) {
  __shared__ __align__(16) signed char lds[3 * 16384];  // 48 KB, A-only ring
  const int bid = blockIdx.x;
  const int lid = (bid & 7) * 128 + (bid >> 3);  // bijective XCD swizzle (1024 % 8 == 0)
  const int bm = lid >> 3;                       // 128 row tiles (M/256)
  const int bn = lid & 7;                        // 8 col tiles (N/256)
  const int tid = threadIdx.x;
  const int wid = tid >> 6;
  const int lane = tid & 63;
  const int wr = wid >> 2, wc = wid & 3;         // wave-tile 128 rows x 64 cols

  // A staging: per gload, thread covers row = wid*32 + j*16 + (lane>>2),
  // dest slot = lane&3 (HW linear). Source logical slot = (lane&3) ^ ((row>>1)&3).
  const int scol = (((lane & 3) ^ ((lane >> 3) & 3)) << 4);
  const signed char* sa = A + (size_t)(bm * 256 + wid * 32 + (lane >> 2)) * KDIM + scol;
  const int dstw = wid << 11;  // wid*2048; HW adds lane*16

  // A ds_read: logical k-slot = lane>>4, row = wr*128 + m*16 + (lane&15)
  // -> physical slot = (lane>>4) ^ ((lane>>1)&3).
  const int rslot = (((lane >> 4) ^ ((lane >> 1) & 3)) << 4);
  const int aRd = (wr * 128 + (lane & 15)) * 64 + rslot;

  // B-frag pointer: frag (bn, kt, nf = wc*4 + j, lane) at
  // ((bn*32+kt)*16 + nf)*1024 + lane*16; per-kt stride 16384, per-j 1024.
  const signed char* bp = Bp + ((size_t)(bn * 32) * 16 + wc * 4) * 1024 + lane * 16;

  v4i acc[8][4] = {};
  v4i fX0, fX1, fX2, fX3, fY0, fY1, fY2, fY3;

  // prologue: S(0), B(0), S(1); vmcnt(2) => S(0)+B(0) done, S(1) in flight.
  STAGE(0, 0)
  LOADB(fX, 0)
  STAGE(1, 1)
  VM2;
  __builtin_amdgcn_s_barrier();
  __builtin_amdgcn_sched_barrier(0);

  // 32 K-tiles; A-ring mod 3, B-set mod 2 -> unroll 6.
  for (int ti = 0; ti < 5; ++ti) {
    const int t = ti * 6;
    KTILE(0, t + 0, fX, fY, 1, 1, VM2)
    KTILE(1, t + 1, fY, fX, 1, 1, VM2)
    KTILE(2, t + 2, fX, fY, 1, 1, VM2)
    KTILE(0, t + 3, fY, fX, 1, 1, VM2)
    KTILE(1, t + 4, fX, fY, 1, 1, VM2)
    KTILE(2, t + 5, fY, fX, 1, 1, VM2)
  }
  KTILE(0, 30, fX, fY, 1, 0, VM0)     // loads B(31); drains S(31)+B(31)
  KTILE(1, 31, fY, fX, 0, 0, VMNONE)  // pure compute

  // epilogue: C/D layout col = lane&15, row = (lane>>4)*4 + reg
  const int col0 = bn * 256 + wc * 64 + (lane & 15);
  const int rbase = bm * 256 + wr * 128 + ((lane >> 4) << 2);
  #pragma unroll
  for (int m = 0; m < 8; ++m) {
    #pragma unroll
    for (int r = 0; r < 4; ++r) {
      const int row = rbase + m * 16 + r;
      const float s = rscale[row];
      float* crow = C + (size_t)row * NDIM + col0;
      #pragma unroll
      for (int n = 0; n < 4; ++n) crow[n * 16] = (float)acc[m][n][r] * s;
    }
  }
}

extern "C" void kernel_launch(void* const* d_in, const int* in_sizes, int n_in,
                              void* d_out, int out_size, void* d_ws, size_t ws_size,
                              hipStream_t stream) {
  const float* x = (const float*)d_in[0];
  const float* W = (const float*)d_in[1];
  float* out = (float*)d_out;
  const int M = in_sizes[0] / KDIM;  // 32768

  signed char* q = (signed char*)d_ws;                       // M*K   = 64 MB
  signed char* Bp = q + (size_t)M * KDIM;                    // N*K   =  4 MB (frag-packed)
  float* rscale = (float*)(Bp + (size_t)NDIM * KDIM);        // M*4   = 128 KB

  quant_rows<<<M, 256, 0, stream>>>(x, q, rscale);
  quant_w_pack<<<(NDIM * KDIM / 16) / 256, 256, 0, stream>>>(W, Bp);
  gemm_i8<<<(M / 256) * (NDIM / 256), 512, 0, stream>>>(q, Bp, rscale, out);
}

// Round 10
// 233.400 us; speedup vs baseline: 1.3040x; 1.2013x over previous
//
#include <hip/hip_runtime.h>

typedef int v4i __attribute__((ext_vector_type(4)));

#define KDIM 2048
#define NDIM 2048

#define GLOAD16(g, l) __builtin_amdgcn_global_load_lds(                      \
    (const __attribute__((address_space(1))) void*)(g),                      \
    (__attribute__((address_space(3))) void*)(l), 16, 0, 0)

// ---------------- quant kernels ----------------

__device__ __forceinline__ int pack4q(float4 v, float s) {
  int a = __float2int_rn(v.x * s);
  int b = __float2int_rn(v.y * s);
  int c = __float2int_rn(v.z * s);
  int d = __float2int_rn(v.w * s);
  a = max(-128, min(127, a)); b = max(-128, min(127, b));
  c = max(-128, min(127, c)); d = max(-128, min(127, d));
  return (a & 0xff) | ((b & 0xff) << 8) | ((c & 0xff) << 16) | ((d & 0xff) << 24);
}

__global__ __launch_bounds__(256) void quant_rows(const float* __restrict__ x,
                                                  signed char* __restrict__ q,
                                                  float* __restrict__ rscale) {
  const int row = blockIdx.x;
  const float4* xr = (const float4*)(x + (size_t)row * KDIM);
  float4 v0 = xr[threadIdx.x];
  float4 v1 = xr[256 + threadIdx.x];
  float m = fmaxf(fmaxf(fabsf(v0.x), fabsf(v0.y)), fmaxf(fabsf(v0.z), fabsf(v0.w)));
  m = fmaxf(m, fmaxf(fmaxf(fabsf(v1.x), fabsf(v1.y)), fmaxf(fabsf(v1.z), fabsf(v1.w))));
  #pragma unroll
  for (int off = 32; off > 0; off >>= 1) m = fmaxf(m, __shfl_xor(m, off));
  __shared__ float red[4];
  if ((threadIdx.x & 63) == 0) red[threadIdx.x >> 6] = m;
  __syncthreads();
  float xmax = fmaxf(fmaxf(red[0], red[1]), fmaxf(red[2], red[3]));
  xmax = fmaxf(xmax, 1e-5f);
  const float scale = 127.0f / xmax;
  int* qr = (int*)(q + (size_t)row * KDIM);
  qr[threadIdx.x] = pack4q(v0, scale);
  qr[256 + threadIdx.x] = pack4q(v1, scale);
  if (threadIdx.x == 0) rscale[row] = xmax * (1.0f / 127.0f);
}

__global__ __launch_bounds__(256) void quant_w(const float* __restrict__ W,
                                               signed char* __restrict__ Wq) {
  const int i = blockIdx.x * 256 + threadIdx.x;
  float4 v = ((const float4*)W)[i];
  int a = (int)v.x, b = (int)v.y, c = (int)v.z, d = (int)v.w;
  ((int*)Wq)[i] = (a & 0xff) | ((b << 8) & 0xff00) | ((c << 16) & 0xff0000) | (d << 24);
}

// ---- 256x256 8-wave i8 GEMM, 4-ring, counted vmcnt, 8-PHASE structure + FIXED swizzle ----
// Round-10: round-2's 2-phase-per-K-tile schedule (2 barriers + lgkmcnt(0) + setprio
// per phase — the m201 wave-stagger structure) combined with the round-4-VERIFIED
// conflict-free swizzle. Regime-gate (m230/m201): swizzle only pays inside this
// phase-split structure; this is the one untested cell.
// Ring: stage S(t) = 4 gloads issued during tile t-3; W(t) boundary vmcnt(8).
// Swizzle: physical 16B slot = logical ^ ((row>>1)&3)  (128-B bank period over
// 64-B rows); applied on global SOURCE (gload_lds dest linear) and ds_read addrs.

#define VM8 asm volatile("s_waitcnt vmcnt(8)" ::: "memory")
#define VM4 asm volatile("s_waitcnt vmcnt(4)" ::: "memory")
#define VM0 asm volatile("s_waitcnt vmcnt(0)" ::: "memory")
#define VMNONE

#define STAGE_A(U, T)                                                        \
  GLOAD16(sa + (T) * 64, lds + (U) * 32768 + dstw);                          \
  GLOAD16(sa + (T) * 64 + 128 * KDIM, lds + (U) * 32768 + 8192 + dstw);
#define STAGE_B(U, T)                                                        \
  GLOAD16(sb + (T) * 64, lds + (U) * 32768 + 16384 + dstw);                  \
  GLOAD16(sb + (T) * 64 + 128 * KDIM, lds + (U) * 32768 + 24576 + dstw);

#define MF(m, n, a) acc[m][n] = __builtin_amdgcn_mfma_i32_16x16x64_i8((a), bf[n], acc[m][n], 0, 0, 0);

#define KTILE(U, T, DOSTAGE, VMEND)                                          \
  {                                                                          \
    /* ---- phase A: read m0-3 + all B, stage A-halves of S(T+3) ---- */     \
    v4i a0 = *(const v4i*)(lds + (U) * 32768 + aRd);                         \
    v4i a1 = *(const v4i*)(lds + (U) * 32768 + aRd + 1024);                  \
    v4i a2 = *(const v4i*)(lds + (U) * 32768 + aRd + 2048);                  \
    v4i a3 = *(const v4i*)(lds + (U) * 32768 + aRd + 3072);                  \
    bf[0] = *(const v4i*)(lds + (U) * 32768 + bRd);                          \
    bf[1] = *(const v4i*)(lds + (U) * 32768 + bRd + 1024);                   \
    bf[2] = *(const v4i*)(lds + (U) * 32768 + bRd + 2048);                   \
    bf[3] = *(const v4i*)(lds + (U) * 32768 + bRd + 3072);                   \
    if (DOSTAGE) { STAGE_A((((U) + 3) & 3), (T) + 3) }                       \
    __builtin_amdgcn_sched_barrier(0);                                       \
    __builtin_amdgcn_s_barrier();                                            \
    asm volatile("s_waitcnt lgkmcnt(0)" ::: "memory");                       \
    __builtin_amdgcn_sched_barrier(0);                                       \
    __builtin_amdgcn_s_setprio(1);                                           \
    MF(0, 0, a0) MF(0, 1, a0) MF(0, 2, a0) MF(0, 3, a0)                      \
    MF(1, 0, a1) MF(1, 1, a1) MF(1, 2, a1) MF(1, 3, a1)                      \
    MF(2, 0, a2) MF(2, 1, a2) MF(2, 2, a2) MF(2, 3, a2)                      \
    MF(3, 0, a3) MF(3, 1, a3) MF(3, 2, a3) MF(3, 3, a3)                      \
    __builtin_amdgcn_s_setprio(0);                                           \
    __builtin_amdgcn_sched_barrier(0);                                       \
    __builtin_amdgcn_s_barrier();                                            \
    /* ---- phase B: read m4-7 (B reused in regs), stage B-halves ---- */    \
    v4i a4 = *(const v4i*)(lds + (U) * 32768 + aRd + 4096);                  \
    v4i a5 = *(const v4i*)(lds + (U) * 32768 + aRd + 5120);                  \
    v4i a6 = *(const v4i*)(lds + (U) * 32768 + aRd + 6144);                  \
    v4i a7 = *(const v4i*)(lds + (U) * 32768 + aRd + 7168);                  \
    if (DOSTAGE) { STAGE_B((((U) + 3) & 3), (T) + 3) }                       \
    __builtin_amdgcn_sched_barrier(0);                                       \
    __builtin_amdgcn_s_barrier();                                            \
    asm volatile("s_waitcnt lgkmcnt(0)" ::: "memory");                       \
    __builtin_amdgcn_sched_barrier(0);                                       \
    __builtin_amdgcn_s_setprio(1);                                           \
    MF(4, 0, a4) MF(4, 1, a4) MF(4, 2, a4) MF(4, 3, a4)                      \
    MF(5, 0, a5) MF(5, 1, a5) MF(5, 2, a5) MF(5, 3, a5)                      \
    MF(6, 0, a6) MF(6, 1, a6) MF(6, 2, a6) MF(6, 3, a6)                      \
    MF(7, 0, a7) MF(7, 1, a7) MF(7, 2, a7) MF(7, 3, a7)                      \
    __builtin_amdgcn_s_setprio(0);                                           \
    __builtin_amdgcn_sched_barrier(0);                                       \
    VMEND;                                                                   \
    __builtin_amdgcn_s_barrier();                                            \
  }

__global__ __launch_bounds__(512, 2) void gemm_i8(const signed char* __restrict__ A,
                                                  const signed char* __restrict__ B,
                                                  const float* __restrict__ rscale,
                                                  float* __restrict__ C) {
  __shared__ __align__(16) signed char lds[131072];
  const int bid = blockIdx.x;
  const int lid = (bid & 7) * 128 + (bid >> 3);  // bijective XCD swizzle (1024 % 8 == 0)
  const int bm = lid >> 3;                       // 128 row tiles
  const int bn = lid & 7;                        // 8 col tiles
  const int tid = threadIdx.x;
  const int wid = tid >> 6;
  const int lane = tid & 63;
  const int wr = wid >> 2, wc = wid & 3;

  // staging: thread covers row = wid*16 + (lane>>2) within each 128-row half,
  // dest slot = lane&3 (HW linear: base + lane*16).
  // source logical slot = (lane&3) ^ ((row>>1)&3) = (lane&3) ^ ((lane>>3)&3).  [R4-verified]
  const int srow = wid * 16 + (lane >> 2);
  const int scol = (((lane & 3) ^ ((lane >> 3) & 3)) << 4);
  const signed char* sa = A + (size_t)(bm * 256 + srow) * KDIM + scol;
  const signed char* sb = B + (size_t)(bn * 256 + srow) * KDIM + scol;
  const int dstw = wid << 10;  // wave-uniform LDS chunk; HW adds lane*16

  // ds_read: logical k-slot = lane>>4, row = ...+(lane&15) -> physical slot
  // = (lane>>4) ^ ((lane>>1)&3).  [R4-verified: SQ_LDS_BANK_CONFLICT = 0]
  const int rslot = (((lane >> 4) ^ ((lane >> 1) & 3)) << 4);
  const int aRd = (wr * 128 + (lane & 15)) * 64 + rslot;
  const int bRd = 16384 + (wc * 64 + (lane & 15)) * 64 + rslot;

  v4i acc[8][4] = {};
  v4i bf[4];

  // prologue: stage S(0), S(1), S(2); W(0)
  STAGE_A(0, 0) STAGE_B(0, 0)
  STAGE_A(1, 1) STAGE_B(1, 1)
  STAGE_A(2, 2) STAGE_B(2, 2)
  VM8;
  __builtin_amdgcn_s_barrier();

  for (int ti = 0; ti < 7; ++ti) {
    const int t = ti * 4;
    KTILE(0, t + 0, 1, VM8)
    KTILE(1, t + 1, 1, VM8)
    KTILE(2, t + 2, 1, VM8)
    KTILE(3, t + 3, 1, VM8)
  }
  KTILE(0, 28, 1, VM8)    // stages S(31)
  KTILE(1, 29, 0, VM4)    // W(30)
  KTILE(2, 30, 0, VM0)    // W(31)
  KTILE(3, 31, 0, VMNONE)

  // epilogue: C/D layout col = lane&15, row = (lane>>4)*4 + reg
  const int col0 = bn * 256 + wc * 64 + (lane & 15);
  const int rbase = bm * 256 + wr * 128 + ((lane >> 4) << 2);
  #pragma unroll
  for (int m = 0; m < 8; ++m) {
    #pragma unroll
    for (int r = 0; r < 4; ++r) {
      const int row = rbase + m * 16 + r;
      const float s = rscale[row];
      float* crow = C + (size_t)row * NDIM + col0;
      #pragma unroll
      for (int n = 0; n < 4; ++n) crow[n * 16] = (float)acc[m][n][r] * s;
    }
  }
}

extern "C" void kernel_launch(void* const* d_in, const int* in_sizes, int n_in,
                              void* d_out, int out_size, void* d_ws, size_t ws_size,
                              hipStream_t stream) {
  const float* x = (const float*)d_in[0];
  const float* W = (const float*)d_in[1];
  float* out = (float*)d_out;
  const int M = in_sizes[0] / KDIM;  // 32768

  signed char* q = (signed char*)d_ws;                       // M*K   = 64 MB
  signed char* Wq = q + (size_t)M * KDIM;                    // N*K   =  4 MB
  float* rscale = (float*)(Wq + (size_t)NDIM * KDIM);        // M*4   = 128 KB

  quant_rows<<<M, 256, 0, stream>>>(x, q, rscale);
  quant_w<<<(NDIM * KDIM / 4) / 256, 256, 0, stream>>>(W, Wq);
  gemm_i8<<<(M / 256) * (NDIM / 256), 512, 0, stream>>>(q, Wq, rscale, out);
}